// Round 7
// baseline (1565.968 us; speedup 1.0000x reference)
//
#include <hip/hip_runtime.h>
#include <hip/hip_bf16.h>
#include <cstdint>
#include <cstddef>

typedef __bf16 v8bf __attribute__((ext_vector_type(8)));
typedef __bf16 v4bf __attribute__((ext_vector_type(4)));
typedef float  f32x4 __attribute__((ext_vector_type(4)));

typedef __attribute__((address_space(1))) void gas_void;
typedef __attribute__((address_space(3))) void las_void;

__device__ __forceinline__ void gload_lds16(const void* g, void* l) {
  __builtin_amdgcn_global_load_lds((const gas_void*)g, (las_void*)l, 16, 0, 0);
}

// flag-aware element read: isf=1 -> f32, else bf16
__device__ __forceinline__ float rdv(const void* p, size_t idx, int isf) {
  return isf ? ((const float*)p)[idx] : (float)((const __bf16*)p)[idx];
}

#define PB 64
#define PM 256
#define PE 1024
#define PH 8
#define PHD 128

// ---------------------------------------------------------------- detect dtype
__global__ void detect_kernel(const void* mask, int* flags) {
  if (threadIdx.x == 0) {
    uint32_t w = *(const uint32_t*)mask;
    flags[0] = ((w >> 16) == 0x3F80u && (w & 0xFFFFu) == 0x3F80u) ? 0 : 1;
  }
}

// ---------------------------------------------------------------- convert att_feats
__global__ __launch_bounds__(256) void convx_kernel(
    const void* __restrict__ src, const int* __restrict__ flags, __bf16* __restrict__ dst) {
  const size_t i = ((size_t)blockIdx.x * 256 + threadIdx.x) * 4;
  if (flags[0]) {
    const float* s = (const float*)src + i;
    v4bf o; o[0] = (__bf16)s[0]; o[1] = (__bf16)s[1]; o[2] = (__bf16)s[2]; o[3] = (__bf16)s[3];
    *(v4bf*)(dst + i) = o;
  } else {
    *(v4bf*)(dst + i) = *(const v4bf*)((const __bf16*)src + i);
  }
}

// ---------------------------------------------------------------- weight transpose
// dst[z*zdst + n*K+k] = src[soff + z*zsrc + k*N + n]; grid (N/64, K/64, Z)
__global__ __launch_bounds__(256) void transpose_kernel(
    const void* __restrict__ src, size_t soff, size_t zsrc, const int* __restrict__ flags,
    __bf16* __restrict__ dst, size_t zdst, int K, int N) {
  __shared__ __bf16 tile[64][66];
  const int isf = flags[0];
  const size_t so = soff + (size_t)blockIdx.z * zsrc;
  __bf16* d = dst + (size_t)blockIdx.z * zdst;
  const int n0 = blockIdx.x * 64, k0 = blockIdx.y * 64;
  const int c = threadIdx.x & 63, r0 = threadIdx.x >> 6;
#pragma unroll
  for (int j = 0; j < 16; ++j) {
    const int r = j * 4 + r0;
    tile[r][c] = (__bf16)rdv(src, so + (size_t)(k0 + r) * N + (n0 + c), isf);
  }
  __syncthreads();
#pragma unroll
  for (int j = 0; j < 16; ++j) {
    const int r = j * 4 + r0;
    d[(size_t)(n0 + r) * K + k0 + c] = tile[c][r];
  }
}

// upd_W/gate_W (L,256,128) -> ugWt[i] = [updT(128x256) | gateT(128x256)]; grid (2,4,8)
__global__ __launch_bounds__(256) void ugtr_kernel(
    const void* __restrict__ updW, const void* __restrict__ gateW,
    const int* __restrict__ flags, __bf16* __restrict__ ugWt) {
  __shared__ __bf16 tile[64][66];
  const int isf = flags[0];
  const int z = blockIdx.z, i = z >> 1, g = z & 1;
  const void* src = g ? gateW : updW;
  const size_t soff = (size_t)i * 32768;
  __bf16* dst = ugWt + (size_t)i * 65536 + g * 32768;
  const int n0 = blockIdx.x * 64, k0 = blockIdx.y * 64;  // N=128, K=256
  const int c = threadIdx.x & 63, r0 = threadIdx.x >> 6;
#pragma unroll
  for (int j = 0; j < 16; ++j) {
    const int r = j * 4 + r0;
    tile[r][c] = (__bf16)rdv(src, soff + (size_t)(k0 + r) * 128 + (n0 + c), isf);
  }
  __syncthreads();
#pragma unroll
  for (int j = 0; j < 16; ++j) {
    const int r = j * 4 + r0;
    dst[(size_t)(n0 + r) * 256 + k0 + c] = tile[c][r];
  }
}

// ---------------------------------------------------------------- GEMM
// A: LDS-staged (gload_lds, XOR-swizzled, depth-2). B: direct global->reg (L2-hot
// panels), prefetched one iteration ahead. LDS 34KB -> 4 blocks/CU.
// C[M,N] = act(A @ Bt^T + bias). AMODE0: A row-major ldA=Kfull. AMODE1: concat[xh|ctx].
// BMODE0: Bt shared. BMODE1: per-(row-block/256) B base. GNF: fused group-norm epilogue.
// SPLITK: blockIdx.z K-slice, f32 partials. SWZ: XCD A-panel-locality block remap.
template<int AMODE, int BMODE, int ACT, bool OUTF32, bool CLAMPM, bool GNF, bool SPLITK, bool SWZ>
__global__ __launch_bounds__(256) void gemm_kernel(
    const __bf16* __restrict__ A, const __bf16* __restrict__ A2,
    const __bf16* __restrict__ Bt,
    const void* __restrict__ bias_a, int offa, const void* __restrict__ bias_b, int offb,
    int bias_split, const int* __restrict__ flags,
    const void* __restrict__ gnw, const void* __restrict__ gnb, int gnoff,
    void* __restrict__ Cout, int K, int Kfull, int Ntot, int Mtot)
{
  __shared__ __align__(16) uint8_t a_s[2][16384];   // 128 rows x 128B, linear dest
  __shared__ float gnsum[128][2];
  __shared__ float gnsq[128][2];
  int bx = blockIdx.x, by = blockIdx.y;
  if (SWZ) {
    const int nx = gridDim.x;
    const int flat = by * nx + bx;
    const int xcd = flat & 7, slot = flat >> 3;
    by = slot & 7;
    bx = (slot >> 3) * 8 + xcd;
  }
  const int mbase = bx * 128;
  const int nbase = by * 128;
  const int koff = SPLITK ? blockIdx.z * K : 0;
  const int tid = threadIdx.x;
  const int wid = tid >> 6, lane = tid & 63;
  const int wr = wid >> 1, wc = wid & 1;

  f32x4 acc[4][4];
#pragma unroll
  for (int m = 0; m < 4; ++m)
#pragma unroll
    for (int n = 0; n < 4; ++n) acc[m][n] = (f32x4){0.f, 0.f, 0.f, 0.f};

  const int nkt = K >> 6;
  const int lrow8 = lane >> 3;
  const int cc = (lane & 7) << 4;

  // B addressing: row offsets fixed per lane; only k varies per step
  const __bf16* bpan = Bt + (BMODE == 1 ? (size_t)(mbase >> 8) * (PHD * PM) : (size_t)0);
  size_t browOff[4];
#pragma unroll
  for (int n = 0; n < 4; ++n)
    browOff[n] = (size_t)(nbase + wc * 64 + n * 16 + (lane & 15)) * Kfull;
  const int bk_lane = (lane >> 4) << 3;   // k element offset within step

  auto STAGE_A = [&](int kt, uint8_t* as) {
    const int kbase = koff + (kt << 6);
#pragma unroll
    for (int j = 0; j < 4; ++j) {
      const int q = wid * 4 + j;
      const int row = q * 8 + lrow8;
      const int c = cc ^ ((row & 7) << 4);   // pre-swizzled source column (bytes)
      const int klocal = c >> 1;
      const __bf16* asrc;
      if (AMODE == 0) {
        int rg = mbase + row;
        if (CLAMPM && rg > Mtot - 1) rg = Mtot - 1;
        asrc = A + (size_t)rg * Kfull + (kbase + klocal);
      } else {
        const int rg = mbase + row;
        const int kg = kbase + klocal;
        if (kg < PHD) {
          const int bh = rg >> 8, mm = rg & 255;
          const int bb = bh >> 3, hh = bh & 7;
          asrc = A + ((size_t)(bb * PM + mm) * PE + hh * PHD + kg);
        } else {
          asrc = A2 + ((size_t)rg * PHD + (kg - PHD));
        }
      }
      gload_lds16(asrc, as + q * 1024);
    }
  };

  v8bf bfr[2][4];
  auto LOADB = [&](int kt) {
    const int kb = koff + (kt << 6);
#pragma unroll
    for (int kk = 0; kk < 2; ++kk)
#pragma unroll
      for (int n = 0; n < 4; ++n)
        bfr[kk][n] = *(const v8bf*)(bpan + browOff[n] + kb + kk * 32 + bk_lane);
  };

  // prologue, issue order pinned: A0 | B0 | A1
  STAGE_A(0, a_s[0]);
  __builtin_amdgcn_sched_barrier(0);
  LOADB(0);
  __builtin_amdgcn_sched_barrier(0);
  if (nkt > 1) STAGE_A(1, a_s[1]);

  for (int kt = 0; kt < nkt; ++kt) {
    // drain A(kt) only: issued-after = B(kt)[8] + A(kt+1)[4 if exists]
    if (kt + 1 < nkt) asm volatile("s_waitcnt vmcnt(12)" ::: "memory");
    else              asm volatile("s_waitcnt vmcnt(8)" ::: "memory");
    __builtin_amdgcn_s_barrier();
    __builtin_amdgcn_sched_barrier(0);
    const uint8_t* ap = a_s[kt & 1];
#pragma unroll
    for (int kk = 0; kk < 2; ++kk) {
      const int co = kk * 64 + ((lane >> 4) << 4);
      v8bf af[4];
#pragma unroll
      for (int m = 0; m < 4; ++m) {
        const int row = wr * 64 + m * 16 + (lane & 15);
        af[m] = *(const v8bf*)(ap + row * 128 + (co ^ ((row & 7) << 4)));
      }
#pragma unroll
      for (int m = 0; m < 4; ++m)
#pragma unroll
        for (int n = 0; n < 4; ++n)
          acc[m][n] = __builtin_amdgcn_mfma_f32_16x16x32_bf16(af[m], bfr[kk][n], acc[m][n], 0, 0, 0);
    }
    __builtin_amdgcn_s_barrier();
    __builtin_amdgcn_sched_barrier(0);
    if (kt + 1 < nkt) LOADB(kt + 1);          // B first (pinned),
    __builtin_amdgcn_sched_barrier(0);
    if (kt + 2 < nkt) STAGE_A(kt + 2, a_s[kt & 1]);  // then A
  }

  const int isf = flags[0];
  if constexpr (GNF) {
    float bv[4];
#pragma unroll
    for (int n = 0; n < 4; ++n) {
      const int col = nbase + wc * 64 + n * 16 + (lane & 15);
      bv[n] = (bias_a != nullptr) ? rdv(bias_a, offa + col, isf) : 0.f;
    }
#pragma unroll
    for (int m = 0; m < 4; ++m)
#pragma unroll
      for (int n = 0; n < 4; ++n)
#pragma unroll
        for (int r = 0; r < 4; ++r) {
          float v = acc[m][n][r] + bv[n];
          if (ACT == 1) v = (v > 0.f) ? v : 1.3f * expm1f(v * (1.0f / 1.3f));
          acc[m][n][r] = v;
        }
#pragma unroll
    for (int m = 0; m < 4; ++m)
#pragma unroll
      for (int r = 0; r < 4; ++r) {
        float s = 0.f, q = 0.f;
#pragma unroll
        for (int n = 0; n < 4; ++n) { s += acc[m][n][r]; q += acc[m][n][r] * acc[m][n][r]; }
#pragma unroll
        for (int off = 1; off < 16; off <<= 1) {
          s += __shfl_xor(s, off, 64); q += __shfl_xor(q, off, 64);
        }
        const int lrow = wr * 64 + m * 16 + ((lane >> 4) << 2) + r;
        if ((lane & 15) == 0) { gnsum[lrow][wc] = s; gnsq[lrow][wc] = q; }
      }
    __syncthreads();
#pragma unroll
    for (int m = 0; m < 4; ++m)
#pragma unroll
      for (int r = 0; r < 4; ++r) {
        const int lrow = wr * 64 + m * 16 + ((lane >> 4) << 2) + r;
        const float mean = (gnsum[lrow][0] + gnsum[lrow][1]) * (1.f / 128.f);
        const float var = (gnsq[lrow][0] + gnsq[lrow][1]) * (1.f / 128.f) - mean * mean;
        const float rstd = rsqrtf(var + 1e-5f);
        const int rg = mbase + lrow;
#pragma unroll
        for (int n = 0; n < 4; ++n) {
          const int col = nbase + wc * 64 + n * 16 + (lane & 15);
          const float o = (acc[m][n][r] - mean) * rstd * rdv(gnw, gnoff + col, isf)
                          + rdv(gnb, gnoff + col, isf);
          ((__bf16*)Cout)[(size_t)rg * Ntot + col] = (__bf16)o;
        }
      }
  } else {
    float* coutF = (float*)Cout + (SPLITK ? (size_t)blockIdx.z * 65536 : (size_t)0);
#pragma unroll
    for (int m = 0; m < 4; ++m) {
      const int rowt = mbase + wr * 64 + m * 16 + ((lane >> 4) << 2);
#pragma unroll
      for (int n = 0; n < 4; ++n) {
        const int col = nbase + wc * 64 + n * 16 + (lane & 15);
        float bvv = 0.f;
        if (bias_a != nullptr)
          bvv = (col < bias_split) ? rdv(bias_a, offa + col, isf)
                                   : rdv(bias_b, offb + col - bias_split, isf);
#pragma unroll
        for (int r = 0; r < 4; ++r) {
          const int rg = rowt + r;
          if (CLAMPM && rg >= Mtot) continue;
          float v = acc[m][n][r] + bvv;
          if (ACT == 1) v = (v > 0.f) ? v : 1.3f * expm1f(v * (1.0f / 1.3f));
          if (OUTF32) coutF[(size_t)rg * Ntot + col] = v;
          else        ((__bf16*)Cout)[(size_t)rg * Ntot + col] = (__bf16)v;
        }
      }
    }
  }
}

// ---------------------------------------------------------------- fused softmax(QK^T)
// grid (CS*PH, PM/64), block 256; chunk-local.
__global__ __launch_bounds__(256) void attn_softmax_kernel(
    const __bf16* __restrict__ xc, const __bf16* __restrict__ memc,
    const void* __restrict__ mask, const int* __restrict__ flags, int b0,
    __bf16* __restrict__ S)
{
  const int bhl = blockIdx.x;
  const int bl = bhl >> 3, h = bhl & 7;
  const int isf = flags[0];
  const int tid = threadIdx.x, wid = tid >> 6, lane = tid & 63;
  const int qbase = blockIdx.y * 64 + wid * 16;
  const size_t xoff = (size_t)bl * PM * PE + h * PHD;

  v8bf a[4];
  {
    const int row = qbase + (lane & 15);
    const int d0 = (lane >> 4) * 8;
    const __bf16* p = xc + xoff + (size_t)row * PE + d0;
#pragma unroll
    for (int k = 0; k < 4; ++k) a[k] = *(const v8bf*)(p + k * 32);
  }
  float mz[16];
#pragma unroll
  for (int t = 0; t < 16; ++t)
    mz[t] = rdv(mask, (size_t)(b0 + bl) * PM + t * 16 + (lane & 15), isf);

  f32x4 acc[16];
#pragma unroll
  for (int t = 0; t < 16; ++t) acc[t] = (f32x4){0.f, 0.f, 0.f, 0.f};
#pragma unroll
  for (int t = 0; t < 16; ++t) {
    const int key = t * 16 + (lane & 15);
    const int d0 = (lane >> 4) * 8;
    const __bf16* p = memc + xoff + (size_t)key * PE + d0;
#pragma unroll
    for (int k = 0; k < 4; ++k) {
      v8bf bb = *(const v8bf*)(p + k * 32);
      acc[t] = __builtin_amdgcn_mfma_f32_16x16x32_bf16(a[k], bb, acc[t], 0, 0, 0);
    }
  }
  const float scale = 0.08838834764831845f;
  float mx[4], sm[4];
#pragma unroll
  for (int r = 0; r < 4; ++r) mx[r] = -3.0e38f;
#pragma unroll
  for (int t = 0; t < 16; ++t)
#pragma unroll
    for (int r = 0; r < 4; ++r) {
      float v = (mz[t] == 0.f) ? -1.0e9f : acc[t][r] * scale;
      acc[t][r] = v;
      mx[r] = fmaxf(mx[r], v);
    }
#pragma unroll
  for (int off = 1; off < 16; off <<= 1)
#pragma unroll
    for (int r = 0; r < 4; ++r) mx[r] = fmaxf(mx[r], __shfl_xor(mx[r], off, 64));
#pragma unroll
  for (int r = 0; r < 4; ++r) sm[r] = 0.f;
#pragma unroll
  for (int t = 0; t < 16; ++t)
#pragma unroll
    for (int r = 0; r < 4; ++r) {
      float e = expf(acc[t][r] - mx[r]);
      acc[t][r] = e; sm[r] += e;
    }
#pragma unroll
  for (int off = 1; off < 16; off <<= 1)
#pragma unroll
    for (int r = 0; r < 4; ++r) sm[r] += __shfl_xor(sm[r], off, 64);
#pragma unroll
  for (int r = 0; r < 4; ++r) sm[r] = 1.f / sm[r];

  const size_t srow = (size_t)bhl * PM;
#pragma unroll
  for (int r = 0; r < 4; ++r) {
    const int q = qbase + (lane >> 4) * 4 + r;
    __bf16* sp = S + (srow + q) * PM;
#pragma unroll
    for (int t = 0; t < 16; ++t)
      sp[t * 16 + (lane & 15)] = (__bf16)(acc[t][r] * sm[r]);
  }
}

// ---------------------------------------------------------------- per-head x transpose
__global__ __launch_bounds__(256) void transpose_x_kernel(
    const __bf16* __restrict__ xc, __bf16* __restrict__ xT)
{
  const int bh = blockIdx.x;
  const int b = bh >> 3, h = bh & 7;
  const int tz = blockIdx.y;
  const int d0 = (tz & 1) * 64, m0 = (tz >> 1) * 64;
  __shared__ __bf16 tile[64][66];
  const int c = threadIdx.x & 63, r0 = threadIdx.x >> 6;
  const __bf16* src = xc + ((size_t)b * PM + m0) * PE + h * PHD + d0;
#pragma unroll
  for (int j = 0; j < 16; ++j) {
    const int r = j * 4 + r0;
    tile[r][c] = src[(size_t)r * PE + c];
  }
  __syncthreads();
  __bf16* dst = xT + ((size_t)bh * PHD + d0) * PM + m0;
#pragma unroll
  for (int j = 0; j < 16; ++j) {
    const int r = j * 4 + r0;
    dst[(size_t)r * PM + c] = tile[c][r];
  }
}

// ---------------------------------------------------------------- gating + layer norm fused
__global__ __launch_bounds__(256) void gatingln_kernel(
    const __bf16* __restrict__ ug, const __bf16* __restrict__ xc,
    const void* __restrict__ w, const void* __restrict__ bz, int off,
    const int* __restrict__ flags, __bf16* __restrict__ xout,
    void* __restrict__ outAux, int row0)
{
  const size_t row = blockIdx.x;                 // local chunk row
  const int tid = threadIdx.x, wid = tid >> 6, lane = tid & 63;
  const int isf = flags[0];
  const int e = tid * 4, h = tid >> 5, d = e & 127;
  const size_t b = row >> 8; const int m = (int)(row & 255);
  const size_t ugrow = ((b * PH + h) * PM + m);
  v4bf fv = *(const v4bf*)(ug + ugrow * 256 + d);
  v4bf gvv = *(const v4bf*)(ug + ugrow * 256 + 128 + d);
  v4bf xv = *(const v4bf*)(xc + row * PE + e);
  float o[4];
#pragma unroll
  for (int r = 0; r < 4; ++r) {
    float f = fv[r], g = gvv[r], xh = xv[r];
    float gs = 1.f / (1.f + expf(-g));
    float ft = tanhf(fmaxf(f, 0.f));
    o[r] = gs * ft + (1.f - gs) * xh;
  }
  float s = o[0] + o[1] + o[2] + o[3];
  float q = o[0] * o[0] + o[1] * o[1] + o[2] * o[2] + o[3] * o[3];
#pragma unroll
  for (int off2 = 1; off2 < 64; off2 <<= 1) {
    s += __shfl_xor(s, off2, 64); q += __shfl_xor(q, off2, 64);
  }
  __shared__ float ss[4], qq[4];
  if (lane == 0) { ss[wid] = s; qq[wid] = q; }
  __syncthreads();
  s = ss[0] + ss[1] + ss[2] + ss[3];
  q = qq[0] + qq[1] + qq[2] + qq[3];
  const float mean = s * (1.f / 1024.f);
  const float var = q * (1.f / 1024.f) - mean * mean;
  const float rstd = rsqrtf(var + 1e-5f);
  float ov[4];
#pragma unroll
  for (int r = 0; r < 4; ++r)
    ov[r] = (o[r] - mean) * rstd * rdv(w, off + e + r, isf) + rdv(bz, off + e + r, isf);
  v4bf vo; vo[0] = (__bf16)ov[0]; vo[1] = (__bf16)ov[1]; vo[2] = (__bf16)ov[2]; vo[3] = (__bf16)ov[3];
  *(v4bf*)(xout + row * PE + e) = vo;
  if (outAux != nullptr) {
    const size_t idx = 65536 + (size_t)(row0 + row) * PE + e;
    if (isf) {
      float* op = (float*)outAux;
      op[idx] = ov[0]; op[idx + 1] = ov[1]; op[idx + 2] = ov[2]; op[idx + 3] = ov[3];
    } else {
      __bf16* op = (__bf16*)outAux;
      op[idx] = (__bf16)ov[0]; op[idx + 1] = (__bf16)ov[1];
      op[idx + 2] = (__bf16)ov[2]; op[idx + 3] = (__bf16)ov[3];
    }
  }
}

// ---------------------------------------------------------------- mask sum / pool
__global__ void msum_kernel(const void* __restrict__ mask, const int* __restrict__ flags,
                            float* __restrict__ msum)
{
  const int b = blockIdx.x, t = threadIdx.x;
  const int isf = flags[0];
  float s = 0.f;
#pragma unroll
  for (int j = 0; j < 4; ++j) s += rdv(mask, (size_t)b * PM + j * 64 + t, isf);
#pragma unroll
  for (int off = 1; off < 64; off <<= 1) s += __shfl_xor(s, off, 64);
  if (t == 0) msum[b] = s;
}

// 1024 threads: 4 wave-quads split the 256 m-rows, LDS reduce
__global__ __launch_bounds__(1024) void pool_kernel(
    const __bf16* __restrict__ x, const void* __restrict__ mask, const int* __restrict__ flags,
    const float* __restrict__ msum, __bf16* __restrict__ feats, int colOff)
{
  __shared__ float red[4][256];
  const int b = blockIdx.x;
  const int el = threadIdx.x & 255;
  const int wq = threadIdx.x >> 8;     // 0..3
  const int e = blockIdx.y * 256 + el;
  const int isf = flags[0];
  const __bf16* p = x + (size_t)b * PM * PE + e;
  float acc = 0.f;
  const int m0 = wq * 64;
  for (int m = m0; m < m0 + 64; m += 4) {
#pragma unroll
    for (int j = 0; j < 4; ++j)
      acc += (float)p[(size_t)(m + j) * PE] * rdv(mask, (size_t)b * PM + m + j, isf);
  }
  red[wq][el] = acc;
  __syncthreads();
  if (wq == 0) {
    float s = red[0][el] + red[1][el] + red[2][el] + red[3][el];
    feats[(size_t)b * (5 * PE) + colOff + e] = (__bf16)(s / msum[b]);
  }
}

// ---------------------------------------------------------------- proj split-K reduce
__global__ __launch_bounds__(256) void projreduce_kernel(
    const float* __restrict__ part, const void* __restrict__ pb,
    const int* __restrict__ flags, float* __restrict__ gvpre)
{
  const int row = blockIdx.x;
  const int c0 = threadIdx.x * 4;
  const int isf = flags[0];
  float a0 = rdv(pb, c0 + 0, isf), a1 = rdv(pb, c0 + 1, isf);
  float a2 = rdv(pb, c0 + 2, isf), a3 = rdv(pb, c0 + 3, isf);
#pragma unroll
  for (int z = 0; z < 8; ++z) {
    const float* p = part + (size_t)z * 65536 + (size_t)row * 1024 + c0;
    a0 += p[0]; a1 += p[1]; a2 += p[2]; a3 += p[3];
  }
  float* op = gvpre + (size_t)row * 1024 + c0;
  op[0] = a0; op[1] = a1; op[2] = a2; op[3] = a3;
}

__global__ __launch_bounds__(256) void ln_final_kernel(
    const float* __restrict__ gin, const void* __restrict__ w, const void* __restrict__ bz,
    const int* __restrict__ flags, void* __restrict__ out)
{
  const size_t row = blockIdx.x;
  const int tid = threadIdx.x, wid = tid >> 6, lane = tid & 63;
  const int isf = flags[0];
  const float* p = gin + row * PE + tid * 4;
  float f0 = p[0], f1 = p[1], f2 = p[2], f3 = p[3];
  float s = f0 + f1 + f2 + f3;
  float q = f0 * f0 + f1 * f1 + f2 * f2 + f3 * f3;
#pragma unroll
  for (int off = 1; off < 64; off <<= 1) {
    s += __shfl_xor(s, off, 64); q += __shfl_xor(q, off, 64);
  }
  __shared__ float ss[4], qq[4];
  if (lane == 0) { ss[wid] = s; qq[wid] = q; }
  __syncthreads();
  s = ss[0] + ss[1] + ss[2] + ss[3];
  q = qq[0] + qq[1] + qq[2] + qq[3];
  const float mean = s * (1.f / 1024.f);
  const float var = q * (1.f / 1024.f) - mean * mean;
  const float rstd = rsqrtf(var + 1e-5f);
  const int e = tid * 4;
#pragma unroll
  for (int j = 0; j < 4; ++j) {
    const float fj = (j == 0 ? f0 : j == 1 ? f1 : j == 2 ? f2 : f3);
    const float ov = (fj - mean) * rstd * rdv(w, e + j, isf) + rdv(bz, e + j, isf);
    if (isf) ((float*)out)[row * PE + e + j] = ov;
    else     ((__bf16*)out)[row * PE + e + j] = (__bf16)ov;
  }
}

// ---------------------------------------------------------------- launch
extern "C" void kernel_launch(void* const* d_in, const int* in_sizes, int n_in,
                              void* d_out, int out_size, void* d_ws, size_t ws_size,
                              hipStream_t stream) {
  const void* att_feats = d_in[1];
  const void* att_mask  = d_in[2];
  const void* mem_W  = d_in[3];
  const void* mem_b  = d_in[4];
  const void* gn_w   = d_in[5];
  const void* gn_b   = d_in[6];
  const void* upd_W  = d_in[7];
  const void* upd_b  = d_in[8];
  const void* gate_W = d_in[9];
  const void* gate_b = d_in[10];
  const void* ln_w   = d_in[11];
  const void* ln_b   = d_in[12];
  const void* proj_W = d_in[13];
  const void* proj_b = d_in[14];
  const void* lnf_w  = d_in[15];
  const void* lnf_b  = d_in[16];

  uint8_t* ws = (uint8_t*)d_ws;
  int*    flags  = (int*)ws;                         // @0
  float*  msum   = (float*)(ws + 4096);
  __bf16* featsb = (__bf16*)(ws + 8192);             // 655,360
  float*  gvpre  = (float*)(ws + 665600);            // 262,144
  __bf16* memWt  = (__bf16*)(ws + 1048576);          // 8,388,608
  __bf16* ugWt   = (__bf16*)(ws + 9437184);          // 524,288
  __bf16* xa0    = (__bf16*)(ws + 10485760);         // 33,554,432
  __bf16* xa     = (__bf16*)(ws + 44040192);         // 33,554,432
  uint8_t* dynb  = ws + 77594624;                    // chunk buffers

  // adaptive chunking by ws_size (deterministic)
  int NC;
  if (ws_size >= (size_t)211812352) NC = 1;
  else if (ws_size >= (size_t)144703488) NC = 2;
  else NC = 4;
  const int CSd = PB / NC;              // batches per chunk
  const int CROWSd = CSd * PM;          // rows per chunk
  const int CGRd = CSd * PH * PM;       // bh-rows per chunk
  const size_t CB = (size_t)CROWSd * PE * 2;   // bytes of one x-chunk
  __bf16* membc = (__bf16*)dynb;                // CB (mem / ctx)
  __bf16* xTgc  = (__bf16*)(dynb + CB);         // CB (xT)
  __bf16* sbufc = (__bf16*)(dynb + 2 * CB);     // 2*CB (S / ug)

  detect_kernel<<<1, 64, 0, stream>>>(att_mask, flags);
  convx_kernel<<<16384, 256, 0, stream>>>(att_feats, flags, xa0);

  transpose_kernel<<<dim3(16, 16, 4), 256, 0, stream>>>(
      mem_W, 0, 1048576, flags, memWt, 1048576, 1024, 1024);
  ugtr_kernel<<<dim3(2, 4, 8), 256, 0, stream>>>(upd_W, gate_W, flags, ugWt);

  msum_kernel<<<64, 64, 0, stream>>>(att_mask, flags, msum);
  pool_kernel<<<dim3(64, 4), 1024, 0, stream>>>(xa0, att_mask, flags, msum, featsb, 0);

  const __bf16* xcur = xa0;
  for (int i = 0; i < 4; ++i) {
    for (int c = 0; c < NC; ++c) {
      const __bf16* xc = xcur + (size_t)c * CROWSd * PE;
      // mem = groupnorm(celu(x @ mem_W + mem_b))  [GN fused; XCD A-panel swizzle]
      gemm_kernel<0, 0, 1, false, false, true, false, true><<<dim3(CROWSd / 128, 8), 256, 0, stream>>>(
          xc, nullptr, memWt + (size_t)i * 1048576, mem_b, i * 1024, nullptr, 0, 1024,
          flags, gn_w, gn_b, i * 1024, membc, 1024, 1024, 1024, CROWSd);
      // per-head x transpose
      transpose_x_kernel<<<dim3(CSd * 8, 8), 256, 0, stream>>>(xc, xTgc);
      // S = softmax(mask(QK^T * scale))
      attn_softmax_kernel<<<dim3(CSd * 8, 4), 256, 0, stream>>>(xc, membc, att_mask, flags,
                                                                c * CSd, sbufc);
      // ctx = S @ xh  (overwrites membc)
      gemm_kernel<0, 1, 0, false, false, false, false, false><<<dim3(CGRd / 128, 1), 256, 0, stream>>>(
          sbufc, nullptr, xTgc, nullptr, 0, nullptr, 0, 128, flags, nullptr, nullptr, 0,
          membc, 256, 256, 128, CGRd);
      // [f|g] = concat[xh,ctx] @ [updW|gateW] + bias  (overwrites sbufc)
      gemm_kernel<1, 0, 0, false, false, false, false, false><<<dim3(CGRd / 128, 2), 256, 0, stream>>>(
          xc, membc, ugWt + (size_t)i * 65536, upd_b, i * 128, gate_b, i * 128, 128,
          flags, nullptr, nullptr, 0, sbufc, 256, 256, 256, CGRd);
      // gated update + head merge + layer norm (fused)
      gatingln_kernel<<<CROWSd, 256, 0, stream>>>(sbufc, xc, ln_w, ln_b, i * 1024, flags,
                                                  xa + (size_t)c * CROWSd * PE,
                                                  (i == 3) ? d_out : nullptr, c * CROWSd);
    }
    pool_kernel<<<dim3(64, 4), 1024, 0, stream>>>(xa, att_mask, flags, msum, featsb,
                                                  (i + 1) * 1024);
    xcur = xa;
  }

  // proj: Bt = proj_W^T (into sbufc region, free now); split-K 8x640 -> partials -> reduce
  __bf16* projWt = sbufc;                 // 10,485,760 B  (sbufc >= 16 MB for all NC)
  float* projPart = (float*)dynb;         // 2,097,152 B   (memb region, free now)
  transpose_kernel<<<dim3(16, 80, 1), 256, 0, stream>>>(proj_W, 0, 0, flags, projWt, 0, 5120, 1024);
  gemm_kernel<0, 0, 0, true, true, false, true, false><<<dim3(1, 8, 8), 256, 0, stream>>>(
      featsb, nullptr, projWt, nullptr, 0, nullptr, 0, 1024,
      flags, nullptr, nullptr, 0, projPart, 640, 5120, 1024, 64);
  projreduce_kernel<<<64, 256, 0, stream>>>(projPart, proj_b, flags, gvpre);
  ln_final_kernel<<<64, 256, 0, stream>>>(gvpre, lnf_w, lnf_b, flags, d_out);
}

// Round 8
// 1329.844 us; speedup vs baseline: 1.1776x; 1.1776x over previous
//
#include <hip/hip_runtime.h>
#include <hip/hip_bf16.h>
#include <cstdint>
#include <cstddef>

typedef __bf16 v8bf __attribute__((ext_vector_type(8)));
typedef __bf16 v4bf __attribute__((ext_vector_type(4)));
typedef float  f32x4 __attribute__((ext_vector_type(4)));

typedef __attribute__((address_space(1))) void gas_void;
typedef __attribute__((address_space(3))) void las_void;

__device__ __forceinline__ void gload_lds16(const void* g, void* l) {
  __builtin_amdgcn_global_load_lds((const gas_void*)g, (las_void*)l, 16, 0, 0);
}

// flag-aware element read: isf=1 -> f32, else bf16
__device__ __forceinline__ float rdv(const void* p, size_t idx, int isf) {
  return isf ? ((const float*)p)[idx] : (float)((const __bf16*)p)[idx];
}

#define PB 64
#define PM 256
#define PE 1024
#define PH 8
#define PHD 128

// ---------------------------------------------------------------- detect dtype
__global__ void detect_kernel(const void* mask, int* flags) {
  if (threadIdx.x == 0) {
    uint32_t w = *(const uint32_t*)mask;
    flags[0] = ((w >> 16) == 0x3F80u && (w & 0xFFFFu) == 0x3F80u) ? 0 : 1;
  }
}

// ---------------------------------------------------------------- convert att_feats
__global__ __launch_bounds__(256) void convx_kernel(
    const void* __restrict__ src, const int* __restrict__ flags, __bf16* __restrict__ dst) {
  const size_t i = ((size_t)blockIdx.x * 256 + threadIdx.x) * 4;
  if (flags[0]) {
    const float* s = (const float*)src + i;
    v4bf o; o[0] = (__bf16)s[0]; o[1] = (__bf16)s[1]; o[2] = (__bf16)s[2]; o[3] = (__bf16)s[3];
    *(v4bf*)(dst + i) = o;
  } else {
    *(v4bf*)(dst + i) = *(const v4bf*)((const __bf16*)src + i);
  }
}

// ---------------------------------------------------------------- weight transpose
// dst[z*zdst + n*K+k] = src[soff + z*zsrc + k*N + n]; grid (N/64, K/64, Z)
__global__ __launch_bounds__(256) void transpose_kernel(
    const void* __restrict__ src, size_t soff, size_t zsrc, const int* __restrict__ flags,
    __bf16* __restrict__ dst, size_t zdst, int K, int N) {
  __shared__ __bf16 tile[64][66];
  const int isf = flags[0];
  const size_t so = soff + (size_t)blockIdx.z * zsrc;
  __bf16* d = dst + (size_t)blockIdx.z * zdst;
  const int n0 = blockIdx.x * 64, k0 = blockIdx.y * 64;
  const int c = threadIdx.x & 63, r0 = threadIdx.x >> 6;
#pragma unroll
  for (int j = 0; j < 16; ++j) {
    const int r = j * 4 + r0;
    tile[r][c] = (__bf16)rdv(src, so + (size_t)(k0 + r) * N + (n0 + c), isf);
  }
  __syncthreads();
#pragma unroll
  for (int j = 0; j < 16; ++j) {
    const int r = j * 4 + r0;
    d[(size_t)(n0 + r) * K + k0 + c] = tile[c][r];
  }
}

// upd_W/gate_W (L,256,128) -> ugWt[i] = [updT(128x256) | gateT(128x256)]; grid (2,4,8)
__global__ __launch_bounds__(256) void ugtr_kernel(
    const void* __restrict__ updW, const void* __restrict__ gateW,
    const int* __restrict__ flags, __bf16* __restrict__ ugWt) {
  __shared__ __bf16 tile[64][66];
  const int isf = flags[0];
  const int z = blockIdx.z, i = z >> 1, g = z & 1;
  const void* src = g ? gateW : updW;
  const size_t soff = (size_t)i * 32768;
  __bf16* dst = ugWt + (size_t)i * 65536 + g * 32768;
  const int n0 = blockIdx.x * 64, k0 = blockIdx.y * 64;  // N=128, K=256
  const int c = threadIdx.x & 63, r0 = threadIdx.x >> 6;
#pragma unroll
  for (int j = 0; j < 16; ++j) {
    const int r = j * 4 + r0;
    tile[r][c] = (__bf16)rdv(src, soff + (size_t)(k0 + r) * 128 + (n0 + c), isf);
  }
  __syncthreads();
#pragma unroll
  for (int j = 0; j < 16; ++j) {
    const int r = j * 4 + r0;
    dst[(size_t)(n0 + r) * 256 + k0 + c] = tile[c][r];
  }
}

// ---------------------------------------------------------------- GEMM (BM=256, 8 waves)
// Tile 256x128, BK=64, depth-2 counted-vmcnt pipeline, A+B LDS-staged (XOR-swizzled).
// C[M,N] = act(A @ Bt^T + bias). AMODE0: A row-major ldA=Kfull. AMODE1: concat[xh|ctx].
// BMODE0: Bt shared. BMODE1: per-256-row-block B base (ctx GEMM; BM==one bh panel).
// GNF: fused group-norm epilogue. SPLITK: blockIdx.z K-slice, f32 partials.
// SWZ: XCD A-panel-locality remap (gridDim.y==8, gridDim.x%8==0).
template<int AMODE, int BMODE, int ACT, bool OUTF32, bool CLAMPM, bool GNF, bool SPLITK, bool SWZ>
__global__ __launch_bounds__(512) void gemm_kernel(
    const __bf16* __restrict__ A, const __bf16* __restrict__ A2,
    const __bf16* __restrict__ Bt,
    const void* __restrict__ bias_a, int offa, const void* __restrict__ bias_b, int offb,
    int bias_split, const int* __restrict__ flags,
    const void* __restrict__ gnw, const void* __restrict__ gnb, int gnoff,
    void* __restrict__ Cout, int K, int Kfull, int Ntot, int Mtot)
{
  __shared__ __align__(16) uint8_t a_s[2][32768];   // 256 rows x 128B, linear dest
  __shared__ __align__(16) uint8_t b_s[2][16384];   // 128 rows x 128B
  __shared__ float gnsum[256][2];
  __shared__ float gnsq[256][2];
  int bx = blockIdx.x, by = blockIdx.y;
  if (SWZ) {
    const int nx = gridDim.x;
    const int flat = by * nx + bx;
    const int xcd = flat & 7, slot = flat >> 3;
    by = slot & 7;
    bx = (slot >> 3) * 8 + xcd;
  }
  const int mbase = bx * 256;
  const int nbase = by * 128;
  const int koff = SPLITK ? blockIdx.z * K : 0;
  const int tid = threadIdx.x;
  const int wid = tid >> 6, lane = tid & 63;
  const int wr = wid >> 1, wc = wid & 1;     // 4x2 wave grid, 64x64 each

  f32x4 acc[4][4];
#pragma unroll
  for (int m = 0; m < 4; ++m)
#pragma unroll
    for (int n = 0; n < 4; ++n) acc[m][n] = (f32x4){0.f, 0.f, 0.f, 0.f};

  const int nkt = K >> 6;
  const int lrow8 = lane >> 3;
  const int cc = (lane & 7) << 4;

  auto STAGE = [&](int kt, uint8_t* as, uint8_t* bs) {
    const int kbase = koff + (kt << 6);
    // A: 256x64 tile = 32 segments of 1KB; 8 waves x 4
#pragma unroll
    for (int j = 0; j < 4; ++j) {
      const int q = wid * 4 + j;
      const int row = q * 8 + lrow8;
      const int c = cc ^ ((row & 7) << 4);   // pre-swizzled source column (bytes)
      const int klocal = c >> 1;
      const __bf16* asrc;
      if (AMODE == 0) {
        int rg = mbase + row;
        if (CLAMPM && rg > Mtot - 1) rg = Mtot - 1;
        asrc = A + (size_t)rg * Kfull + (kbase + klocal);
      } else {
        const int rg = mbase + row;
        const int kg = kbase + klocal;
        if (kg < PHD) {
          const int bh = rg >> 8, mm = rg & 255;
          const int bb = bh >> 3, hh = bh & 7;
          asrc = A + ((size_t)(bb * PM + mm) * PE + hh * PHD + kg);
        } else {
          asrc = A2 + ((size_t)rg * PHD + (kg - PHD));
        }
      }
      gload_lds16(asrc, as + q * 1024);
    }
    // B: 128x64 tile = 16 segments; 8 waves x 2
#pragma unroll
    for (int j = 0; j < 2; ++j) {
      const int q = wid * 2 + j;
      const int row = q * 8 + lrow8;
      const int c = cc ^ ((row & 7) << 4);
      const int klocal = c >> 1;
      const __bf16* bsrc;
      if (BMODE == 0) {
        bsrc = Bt + (size_t)(nbase + row) * Kfull + (kbase + klocal);
      } else {
        bsrc = Bt + (size_t)(mbase >> 8) * (PHD * PM)
                  + (size_t)(nbase + row) * Kfull + (kbase + klocal);
      }
      gload_lds16(bsrc, bs + q * 1024);
    }
  };

  // prologue: 2 tiles in flight (12 VMEM ops/thread)
  STAGE(0, a_s[0], b_s[0]);
  if (nkt > 1) STAGE(1, a_s[1], b_s[1]);

  for (int kt = 0; kt < nkt; ++kt) {
    // drain tile kt only (6 loads/thread); tile kt+1's 6 stay in flight
    if (kt + 1 < nkt) asm volatile("s_waitcnt vmcnt(6)" ::: "memory");
    else              asm volatile("s_waitcnt vmcnt(0)" ::: "memory");
    __builtin_amdgcn_s_barrier();
    __builtin_amdgcn_sched_barrier(0);
    const uint8_t* ap = a_s[kt & 1];
    const uint8_t* bp = b_s[kt & 1];
#pragma unroll
    for (int kk = 0; kk < 2; ++kk) {
      const int co = kk * 64 + ((lane >> 4) << 4);
      v8bf af[4], bfr[4];
#pragma unroll
      for (int m = 0; m < 4; ++m) {
        const int row = wr * 64 + m * 16 + (lane & 15);
        af[m] = *(const v8bf*)(ap + row * 128 + (co ^ ((row & 7) << 4)));
      }
#pragma unroll
      for (int n = 0; n < 4; ++n) {
        const int row = wc * 64 + n * 16 + (lane & 15);
        bfr[n] = *(const v8bf*)(bp + row * 128 + (co ^ ((row & 7) << 4)));
      }
#pragma unroll
      for (int m = 0; m < 4; ++m)
#pragma unroll
        for (int n = 0; n < 4; ++n)
          acc[m][n] = __builtin_amdgcn_mfma_f32_16x16x32_bf16(af[m], bfr[n], acc[m][n], 0, 0, 0);
    }
    __builtin_amdgcn_s_barrier();
    __builtin_amdgcn_sched_barrier(0);
    if (kt + 2 < nkt) STAGE(kt + 2, a_s[kt & 1], b_s[kt & 1]);
  }

  const int isf = flags[0];
  if constexpr (GNF) {
    float bv[4];
#pragma unroll
    for (int n = 0; n < 4; ++n) {
      const int col = nbase + wc * 64 + n * 16 + (lane & 15);
      bv[n] = (bias_a != nullptr) ? rdv(bias_a, offa + col, isf) : 0.f;
    }
#pragma unroll
    for (int m = 0; m < 4; ++m)
#pragma unroll
      for (int n = 0; n < 4; ++n)
#pragma unroll
        for (int r = 0; r < 4; ++r) {
          float v = acc[m][n][r] + bv[n];
          if (ACT == 1) v = (v > 0.f) ? v : 1.3f * expm1f(v * (1.0f / 1.3f));
          acc[m][n][r] = v;
        }
#pragma unroll
    for (int m = 0; m < 4; ++m)
#pragma unroll
      for (int r = 0; r < 4; ++r) {
        float s = 0.f, q = 0.f;
#pragma unroll
        for (int n = 0; n < 4; ++n) { s += acc[m][n][r]; q += acc[m][n][r] * acc[m][n][r]; }
#pragma unroll
        for (int off = 1; off < 16; off <<= 1) {
          s += __shfl_xor(s, off, 64); q += __shfl_xor(q, off, 64);
        }
        const int lrow = wr * 64 + m * 16 + ((lane >> 4) << 2) + r;
        if ((lane & 15) == 0) { gnsum[lrow][wc] = s; gnsq[lrow][wc] = q; }
      }
    __syncthreads();
#pragma unroll
    for (int m = 0; m < 4; ++m)
#pragma unroll
      for (int r = 0; r < 4; ++r) {
        const int lrow = wr * 64 + m * 16 + ((lane >> 4) << 2) + r;
        const float mean = (gnsum[lrow][0] + gnsum[lrow][1]) * (1.f / 128.f);
        const float var = (gnsq[lrow][0] + gnsq[lrow][1]) * (1.f / 128.f) - mean * mean;
        const float rstd = rsqrtf(var + 1e-5f);
        const int rg = mbase + lrow;
#pragma unroll
        for (int n = 0; n < 4; ++n) {
          const int col = nbase + wc * 64 + n * 16 + (lane & 15);
          const float o = (acc[m][n][r] - mean) * rstd * rdv(gnw, gnoff + col, isf)
                          + rdv(gnb, gnoff + col, isf);
          ((__bf16*)Cout)[(size_t)rg * Ntot + col] = (__bf16)o;
        }
      }
  } else {
    float* coutF = (float*)Cout + (SPLITK ? (size_t)blockIdx.z * 65536 : (size_t)0);
#pragma unroll
    for (int m = 0; m < 4; ++m) {
      const int rowt = mbase + wr * 64 + m * 16 + ((lane >> 4) << 2);
#pragma unroll
      for (int n = 0; n < 4; ++n) {
        const int col = nbase + wc * 64 + n * 16 + (lane & 15);
        float bvv = 0.f;
        if (bias_a != nullptr)
          bvv = (col < bias_split) ? rdv(bias_a, offa + col, isf)
                                   : rdv(bias_b, offb + col - bias_split, isf);
#pragma unroll
        for (int r = 0; r < 4; ++r) {
          const int rg = rowt + r;
          if (CLAMPM && rg >= Mtot) continue;
          float v = acc[m][n][r] + bvv;
          if (ACT == 1) v = (v > 0.f) ? v : 1.3f * expm1f(v * (1.0f / 1.3f));
          if (OUTF32) coutF[(size_t)rg * Ntot + col] = v;
          else        ((__bf16*)Cout)[(size_t)rg * Ntot + col] = (__bf16)v;
        }
      }
    }
  }
}

// ---------------------------------------------------------------- fused softmax(QK^T)
// grid (CS*PH, PM/64), block 256; chunk-local.
__global__ __launch_bounds__(256) void attn_softmax_kernel(
    const __bf16* __restrict__ xc, const __bf16* __restrict__ memc,
    const void* __restrict__ mask, const int* __restrict__ flags, int b0,
    __bf16* __restrict__ S)
{
  const int bhl = blockIdx.x;
  const int bl = bhl >> 3, h = bhl & 7;
  const int isf = flags[0];
  const int tid = threadIdx.x, wid = tid >> 6, lane = tid & 63;
  const int qbase = blockIdx.y * 64 + wid * 16;
  const size_t xoff = (size_t)bl * PM * PE + h * PHD;

  v8bf a[4];
  {
    const int row = qbase + (lane & 15);
    const int d0 = (lane >> 4) * 8;
    const __bf16* p = xc + xoff + (size_t)row * PE + d0;
#pragma unroll
    for (int k = 0; k < 4; ++k) a[k] = *(const v8bf*)(p + k * 32);
  }
  float mz[16];
#pragma unroll
  for (int t = 0; t < 16; ++t)
    mz[t] = rdv(mask, (size_t)(b0 + bl) * PM + t * 16 + (lane & 15), isf);

  f32x4 acc[16];
#pragma unroll
  for (int t = 0; t < 16; ++t) acc[t] = (f32x4){0.f, 0.f, 0.f, 0.f};
#pragma unroll
  for (int t = 0; t < 16; ++t) {
    const int key = t * 16 + (lane & 15);
    const int d0 = (lane >> 4) * 8;
    const __bf16* p = memc + xoff + (size_t)key * PE + d0;
#pragma unroll
    for (int k = 0; k < 4; ++k) {
      v8bf bb = *(const v8bf*)(p + k * 32);
      acc[t] = __builtin_amdgcn_mfma_f32_16x16x32_bf16(a[k], bb, acc[t], 0, 0, 0);
    }
  }
  const float scale = 0.08838834764831845f;
  float mx[4], sm[4];
#pragma unroll
  for (int r = 0; r < 4; ++r) mx[r] = -3.0e38f;
#pragma unroll
  for (int t = 0; t < 16; ++t)
#pragma unroll
    for (int r = 0; r < 4; ++r) {
      float v = (mz[t] == 0.f) ? -1.0e9f : acc[t][r] * scale;
      acc[t][r] = v;
      mx[r] = fmaxf(mx[r], v);
    }
#pragma unroll
  for (int off = 1; off < 16; off <<= 1)
#pragma unroll
    for (int r = 0; r < 4; ++r) mx[r] = fmaxf(mx[r], __shfl_xor(mx[r], off, 64));
#pragma unroll
  for (int r = 0; r < 4; ++r) sm[r] = 0.f;
#pragma unroll
  for (int t = 0; t < 16; ++t)
#pragma unroll
    for (int r = 0; r < 4; ++r) {
      float e = expf(acc[t][r] - mx[r]);
      acc[t][r] = e; sm[r] += e;
    }
#pragma unroll
  for (int off = 1; off < 16; off <<= 1)
#pragma unroll
    for (int r = 0; r < 4; ++r) sm[r] += __shfl_xor(sm[r], off, 64);
#pragma unroll
  for (int r = 0; r < 4; ++r) sm[r] = 1.f / sm[r];

  const size_t srow = (size_t)bhl * PM;
#pragma unroll
  for (int r = 0; r < 4; ++r) {
    const int q = qbase + (lane >> 4) * 4 + r;
    __bf16* sp = S + (srow + q) * PM;
#pragma unroll
    for (int t = 0; t < 16; ++t)
      sp[t * 16 + (lane & 15)] = (__bf16)(acc[t][r] * sm[r]);
  }
}

// ---------------------------------------------------------------- per-head x transpose
__global__ __launch_bounds__(256) void transpose_x_kernel(
    const __bf16* __restrict__ xc, __bf16* __restrict__ xT)
{
  const int bh = blockIdx.x;
  const int b = bh >> 3, h = bh & 7;
  const int tz = blockIdx.y;
  const int d0 = (tz & 1) * 64, m0 = (tz >> 1) * 64;
  __shared__ __bf16 tile[64][66];
  const int c = threadIdx.x & 63, r0 = threadIdx.x >> 6;
  const __bf16* src = xc + ((size_t)b * PM + m0) * PE + h * PHD + d0;
#pragma unroll
  for (int j = 0; j < 16; ++j) {
    const int r = j * 4 + r0;
    tile[r][c] = src[(size_t)r * PE + c];
  }
  __syncthreads();
  __bf16* dst = xT + ((size_t)bh * PHD + d0) * PM + m0;
#pragma unroll
  for (int j = 0; j < 16; ++j) {
    const int r = j * 4 + r0;
    dst[(size_t)r * PM + c] = tile[c][r];
  }
}

// ---------------------------------------------------------------- gating + layer norm fused
__global__ __launch_bounds__(256) void gatingln_kernel(
    const __bf16* __restrict__ ug, const __bf16* __restrict__ xc,
    const void* __restrict__ w, const void* __restrict__ bz, int off,
    const int* __restrict__ flags, __bf16* __restrict__ xout,
    void* __restrict__ outAux, int row0)
{
  const size_t row = blockIdx.x;                 // local chunk row
  const int tid = threadIdx.x, wid = tid >> 6, lane = tid & 63;
  const int isf = flags[0];
  const int e = tid * 4, h = tid >> 5, d = e & 127;
  const size_t b = row >> 8; const int m = (int)(row & 255);
  const size_t ugrow = ((b * PH + h) * PM + m);
  v4bf fv = *(const v4bf*)(ug + ugrow * 256 + d);
  v4bf gvv = *(const v4bf*)(ug + ugrow * 256 + 128 + d);
  v4bf xv = *(const v4bf*)(xc + row * PE + e);
  float o[4];
#pragma unroll
  for (int r = 0; r < 4; ++r) {
    float f = fv[r], g = gvv[r], xh = xv[r];
    float gs = 1.f / (1.f + expf(-g));
    float ft = tanhf(fmaxf(f, 0.f));
    o[r] = gs * ft + (1.f - gs) * xh;
  }
  float s = o[0] + o[1] + o[2] + o[3];
  float q = o[0] * o[0] + o[1] * o[1] + o[2] * o[2] + o[3] * o[3];
#pragma unroll
  for (int off2 = 1; off2 < 64; off2 <<= 1) {
    s += __shfl_xor(s, off2, 64); q += __shfl_xor(q, off2, 64);
  }
  __shared__ float ss[4], qq[4];
  if (lane == 0) { ss[wid] = s; qq[wid] = q; }
  __syncthreads();
  s = ss[0] + ss[1] + ss[2] + ss[3];
  q = qq[0] + qq[1] + qq[2] + qq[3];
  const float mean = s * (1.f / 1024.f);
  const float var = q * (1.f / 1024.f) - mean * mean;
  const float rstd = rsqrtf(var + 1e-5f);
  float ov[4];
#pragma unroll
  for (int r = 0; r < 4; ++r)
    ov[r] = (o[r] - mean) * rstd * rdv(w, off + e + r, isf) + rdv(bz, off + e + r, isf);
  v4bf vo; vo[0] = (__bf16)ov[0]; vo[1] = (__bf16)ov[1]; vo[2] = (__bf16)ov[2]; vo[3] = (__bf16)ov[3];
  *(v4bf*)(xout + row * PE + e) = vo;
  if (outAux != nullptr) {
    const size_t idx = 65536 + (size_t)(row0 + row) * PE + e;
    if (isf) {
      float* op = (float*)outAux;
      op[idx] = ov[0]; op[idx + 1] = ov[1]; op[idx + 2] = ov[2]; op[idx + 3] = ov[3];
    } else {
      __bf16* op = (__bf16*)outAux;
      op[idx] = (__bf16)ov[0]; op[idx + 1] = (__bf16)ov[1];
      op[idx + 2] = (__bf16)ov[2]; op[idx + 3] = (__bf16)ov[3];
    }
  }
}

// ---------------------------------------------------------------- mask sum / pool
__global__ void msum_kernel(const void* __restrict__ mask, const int* __restrict__ flags,
                            float* __restrict__ msum)
{
  const int b = blockIdx.x, t = threadIdx.x;
  const int isf = flags[0];
  float s = 0.f;
#pragma unroll
  for (int j = 0; j < 4; ++j) s += rdv(mask, (size_t)b * PM + j * 64 + t, isf);
#pragma unroll
  for (int off = 1; off < 64; off <<= 1) s += __shfl_xor(s, off, 64);
  if (t == 0) msum[b] = s;
}

// 1024 threads: 4 wave-quads split the 256 m-rows, LDS reduce
__global__ __launch_bounds__(1024) void pool_kernel(
    const __bf16* __restrict__ x, const void* __restrict__ mask, const int* __restrict__ flags,
    const float* __restrict__ msum, __bf16* __restrict__ feats, int colOff)
{
  __shared__ float red[4][256];
  const int b = blockIdx.x;
  const int el = threadIdx.x & 255;
  const int wq = threadIdx.x >> 8;     // 0..3
  const int e = blockIdx.y * 256 + el;
  const int isf = flags[0];
  const __bf16* p = x + (size_t)b * PM * PE + e;
  float acc = 0.f;
  const int m0 = wq * 64;
  for (int m = m0; m < m0 + 64; m += 4) {
#pragma unroll
    for (int j = 0; j < 4; ++j)
      acc += (float)p[(size_t)(m + j) * PE] * rdv(mask, (size_t)b * PM + m + j, isf);
  }
  red[wq][el] = acc;
  __syncthreads();
  if (wq == 0) {
    float s = red[0][el] + red[1][el] + red[2][el] + red[3][el];
    feats[(size_t)b * (5 * PE) + colOff + e] = (__bf16)(s / msum[b]);
  }
}

// ---------------------------------------------------------------- proj split-K reduce
__global__ __launch_bounds__(256) void projreduce_kernel(
    const float* __restrict__ part, const void* __restrict__ pb,
    const int* __restrict__ flags, float* __restrict__ gvpre)
{
  const int row = blockIdx.x;
  const int c0 = threadIdx.x * 4;
  const int isf = flags[0];
  float a0 = rdv(pb, c0 + 0, isf), a1 = rdv(pb, c0 + 1, isf);
  float a2 = rdv(pb, c0 + 2, isf), a3 = rdv(pb, c0 + 3, isf);
#pragma unroll
  for (int z = 0; z < 8; ++z) {
    const float* p = part + (size_t)z * 65536 + (size_t)row * 1024 + c0;
    a0 += p[0]; a1 += p[1]; a2 += p[2]; a3 += p[3];
  }
  float* op = gvpre + (size_t)row * 1024 + c0;
  op[0] = a0; op[1] = a1; op[2] = a2; op[3] = a3;
}

__global__ __launch_bounds__(256) void ln_final_kernel(
    const float* __restrict__ gin, const void* __restrict__ w, const void* __restrict__ bz,
    const int* __restrict__ flags, void* __restrict__ out)
{
  const size_t row = blockIdx.x;
  const int tid = threadIdx.x, wid = tid >> 6, lane = tid & 63;
  const int isf = flags[0];
  const float* p = gin + row * PE + tid * 4;
  float f0 = p[0], f1 = p[1], f2 = p[2], f3 = p[3];
  float s = f0 + f1 + f2 + f3;
  float q = f0 * f0 + f1 * f1 + f2 * f2 + f3 * f3;
#pragma unroll
  for (int off = 1; off < 64; off <<= 1) {
    s += __shfl_xor(s, off, 64); q += __shfl_xor(q, off, 64);
  }
  __shared__ float ss[4], qq[4];
  if (lane == 0) { ss[wid] = s; qq[wid] = q; }
  __syncthreads();
  s = ss[0] + ss[1] + ss[2] + ss[3];
  q = qq[0] + qq[1] + qq[2] + qq[3];
  const float mean = s * (1.f / 1024.f);
  const float var = q * (1.f / 1024.f) - mean * mean;
  const float rstd = rsqrtf(var + 1e-5f);
  const int e = tid * 4;
#pragma unroll
  for (int j = 0; j < 4; ++j) {
    const float fj = (j == 0 ? f0 : j == 1 ? f1 : j == 2 ? f2 : f3);
    const float ov = (fj - mean) * rstd * rdv(w, e + j, isf) + rdv(bz, e + j, isf);
    if (isf) ((float*)out)[row * PE + e + j] = ov;
    else     ((__bf16*)out)[row * PE + e + j] = (__bf16)ov;
  }
}

// ---------------------------------------------------------------- launch
extern "C" void kernel_launch(void* const* d_in, const int* in_sizes, int n_in,
                              void* d_out, int out_size, void* d_ws, size_t ws_size,
                              hipStream_t stream) {
  const void* att_feats = d_in[1];
  const void* att_mask  = d_in[2];
  const void* mem_W  = d_in[3];
  const void* mem_b  = d_in[4];
  const void* gn_w   = d_in[5];
  const void* gn_b   = d_in[6];
  const void* upd_W  = d_in[7];
  const void* upd_b  = d_in[8];
  const void* gate_W = d_in[9];
  const void* gate_b = d_in[10];
  const void* ln_w   = d_in[11];
  const void* ln_b   = d_in[12];
  const void* proj_W = d_in[13];
  const void* proj_b = d_in[14];
  const void* lnf_w  = d_in[15];
  const void* lnf_b  = d_in[16];

  uint8_t* ws = (uint8_t*)d_ws;
  int*    flags  = (int*)ws;                         // @0
  float*  msum   = (float*)(ws + 4096);
  __bf16* featsb = (__bf16*)(ws + 8192);             // 655,360
  float*  gvpre  = (float*)(ws + 665600);            // 262,144
  __bf16* memWt  = (__bf16*)(ws + 1048576);          // 8,388,608
  __bf16* ugWt   = (__bf16*)(ws + 9437184);          // 524,288
  __bf16* xa0    = (__bf16*)(ws + 10485760);         // 33,554,432
  __bf16* xa     = (__bf16*)(ws + 44040192);         // 33,554,432
  uint8_t* dynb  = ws + 77594624;                    // chunk buffers

  // adaptive chunking by ws_size (deterministic)
  int NC;
  if (ws_size >= (size_t)211812352) NC = 1;
  else if (ws_size >= (size_t)144703488) NC = 2;
  else NC = 4;
  const int CSd = PB / NC;              // batches per chunk
  const int CROWSd = CSd * PM;          // rows per chunk
  const int CGRd = CSd * PH * PM;       // bh-rows per chunk
  const size_t CB = (size_t)CROWSd * PE * 2;   // bytes of one x-chunk
  __bf16* membc = (__bf16*)dynb;                // CB (mem / ctx)
  __bf16* xTgc  = (__bf16*)(dynb + CB);         // CB (xT)
  __bf16* sbufc = (__bf16*)(dynb + 2 * CB);     // 2*CB (S / ug)

  detect_kernel<<<1, 64, 0, stream>>>(att_mask, flags);
  convx_kernel<<<16384, 256, 0, stream>>>(att_feats, flags, xa0);

  transpose_kernel<<<dim3(16, 16, 4), 256, 0, stream>>>(
      mem_W, 0, 1048576, flags, memWt, 1048576, 1024, 1024);
  ugtr_kernel<<<dim3(2, 4, 8), 256, 0, stream>>>(upd_W, gate_W, flags, ugWt);

  msum_kernel<<<64, 64, 0, stream>>>(att_mask, flags, msum);
  pool_kernel<<<dim3(64, 4), 1024, 0, stream>>>(xa0, att_mask, flags, msum, featsb, 0);

  const __bf16* xcur = xa0;
  for (int i = 0; i < 4; ++i) {
    for (int c = 0; c < NC; ++c) {
      const __bf16* xc = xcur + (size_t)c * CROWSd * PE;
      // mem = groupnorm(celu(x @ mem_W + mem_b))  [GN fused; XCD A-panel swizzle]
      gemm_kernel<0, 0, 1, false, false, true, false, true><<<dim3(CROWSd / 256, 8), 512, 0, stream>>>(
          xc, nullptr, memWt + (size_t)i * 1048576, mem_b, i * 1024, nullptr, 0, 1024,
          flags, gn_w, gn_b, i * 1024, membc, 1024, 1024, 1024, CROWSd);
      // per-head x transpose
      transpose_x_kernel<<<dim3(CSd * 8, 8), 256, 0, stream>>>(xc, xTgc);
      // S = softmax(mask(QK^T * scale))
      attn_softmax_kernel<<<dim3(CSd * 8, 4), 256, 0, stream>>>(xc, membc, att_mask, flags,
                                                                c * CSd, sbufc);
      // ctx = S @ xh  (overwrites membc)
      gemm_kernel<0, 1, 0, false, false, false, false, false><<<dim3(CGRd / 256, 1), 512, 0, stream>>>(
          sbufc, nullptr, xTgc, nullptr, 0, nullptr, 0, 128, flags, nullptr, nullptr, 0,
          membc, 256, 256, 128, CGRd);
      // [f|g] = concat[xh,ctx] @ [updW|gateW] + bias  (overwrites sbufc)
      gemm_kernel<1, 0, 0, false, false, false, false, false><<<dim3(CGRd / 256, 2), 512, 0, stream>>>(
          xc, membc, ugWt + (size_t)i * 65536, upd_b, i * 128, gate_b, i * 128, 128,
          flags, nullptr, nullptr, 0, sbufc, 256, 256, 256, CGRd);
      // gated update + head merge + layer norm (fused)
      gatingln_kernel<<<CROWSd, 256, 0, stream>>>(sbufc, xc, ln_w, ln_b, i * 1024, flags,
                                                  xa + (size_t)c * CROWSd * PE,
                                                  (i == 3) ? d_out : nullptr, c * CROWSd);
    }
    pool_kernel<<<dim3(64, 4), 1024, 0, stream>>>(xa, att_mask, flags, msum, featsb,
                                                  (i + 1) * 1024);
    xcur = xa;
  }

  // proj: Bt = proj_W^T (into sbufc region, free now); split-K 8x640 -> partials -> reduce
  __bf16* projWt = sbufc;                 // 10,485,760 B  (sbufc >= 16 MB for all NC)
  float* projPart = (float*)dynb;         // 2,097,152 B   (memb region, free now)
  transpose_kernel<<<dim3(16, 80, 1), 256, 0, stream>>>(proj_W, 0, 0, flags, projWt, 0, 5120, 1024);
  gemm_kernel<0, 0, 0, true, true, false, true, false><<<dim3(1, 8, 8), 512, 0, stream>>>(
      featsb, nullptr, projWt, nullptr, 0, nullptr, 0, 1024,
      flags, nullptr, nullptr, 0, projPart, 640, 5120, 1024, 64);
  projreduce_kernel<<<64, 256, 0, stream>>>(projPart, proj_b, flags, gvpre);
  ln_final_kernel<<<64, 256, 0, stream>>>(gvpre, lnf_w, lnf_b, flags, d_out);
}